// Round 1
// 1238.259 us; speedup vs baseline: 1.0985x; 1.0985x over previous
//
#include <hip/hip_runtime.h>
#include <math.h>

#define HH   128   // H
#define KK   256   // 2H = GEMM K
#define NC   512   // GEMM N: [s_r | s_z | i_n | h_n]
#define MB   32    // edges per block (GEMM M-tile)
#define TBK  512   // encoded-table bucket coverage

typedef short bf16x8 __attribute__((ext_vector_type(8)));
typedef float f32x4  __attribute__((ext_vector_type(4)));

__device__ __forceinline__ float bf2f(short s) {
  union { unsigned u; float f; } v; v.u = ((unsigned)(unsigned short)s) << 16; return v.f;
}
__device__ __forceinline__ short f2bf(float f) {
  union { float f; unsigned u; } v; v.f = f; return (short)(v.u >> 16);  // truncate
}

// ---------------- small prep kernels ----------------

__global__ void k_lastpos(const int* __restrict__ rel, const int* __restrict__ src,
                          int* __restrict__ lastpos, int N, int E) {
  int e = blockIdx.x * 256 + threadIdx.x;
  if (e >= E) return;
  atomicMax(&lastpos[rel[e] * N + src[e]], e);
}

__global__ void k_count(const int* __restrict__ rel, const int* __restrict__ src,
                        const int* __restrict__ lastpos, int* __restrict__ meta,
                        int N, int E) {
  int e = blockIdx.x * 256 + threadIdx.x;
  if (e >= E) return;
  int r = rel[e];
  if (lastpos[r * N + src[e]] == e) atomicAdd(&meta[r], 1);
}

// meta layout (ints): [0..15]=counts, [16..32]=offs, [33..49]=goff, [50]=total_groups, [51..66]=cursor
__global__ void k_scan(int* __restrict__ meta, int R) {
  if (threadIdx.x != 0 || blockIdx.x != 0) return;
  int off = 0, g = 0;
  meta[16] = 0; meta[33] = 0;
  for (int r = 0; r < R; r++) {
    int c = meta[r];
    off += c;
    g += (c + MB - 1) / MB;
    meta[16 + r + 1] = off;
    meta[33 + r + 1] = g;
    meta[51 + r] = meta[16 + r];  // cursor = offs[r]
  }
  meta[50] = g;
}

__global__ void k_scatter(const int* __restrict__ rel, const int* __restrict__ src,
                          const int* __restrict__ lastpos, int* __restrict__ meta,
                          int* __restrict__ bin, int N, int E) {
  int e = blockIdx.x * 256 + threadIdx.x;
  if (e >= E) return;
  int r = rel[e];
  if (lastpos[r * N + src[e]] == e) {
    int p = atomicAdd(&meta[51 + r], 1);
    bin[p] = e;
  }
}

// Fused + split-precision weight table.
// WT[r][c][j], c in [0,512), j in [0,256), stored K-contiguous (bf16 hi and lo).
//   c <  256 : W_ih[r][c][j]  (+ W_hh[r][c][j-128] for j>=128)   -> s_r, s_z columns
//   c <  384 : W_ih[r][c][j]                                      -> i_n columns
//   else     : (j>=128) ? W_hh[r][c-128][j-128] : 0               -> h_n columns
__global__ void k_wprep(const float* __restrict__ Wih, const float* __restrict__ Whh,
                        short* __restrict__ WThi, short* __restrict__ WTlo, int R) {
  int idx = blockIdx.x * 256 + threadIdx.x;
  int total = R * NC * KK;
  if (idx >= total) return;
  int r = idx / (NC * KK);
  int rem = idx - r * (NC * KK);
  int c = rem >> 8;     // 0..511
  int j = rem & 255;    // 0..255
  float w = 0.0f;
  if (c < 256) {
    w = Wih[((size_t)r * 384 + c) * 256 + j];
    if (j >= 128) w += Whh[((size_t)r * 384 + c) * 128 + (j - 128)];
  } else if (c < 384) {
    w = Wih[((size_t)r * 384 + c) * 256 + j];
  } else {
    if (j >= 128) w = Whh[((size_t)r * 384 + (c - 128)) * 128 + (j - 128)];
  }
  short hi = f2bf(w);
  short lo = f2bf(w - bf2f(hi));
  WThi[idx] = hi;
  WTlo[idx] = lo;
}

// ET[r][b][h] = enc_W[r][h][b] + enc_b[r][h]   for b < TBK
__global__ void k_et(const float* __restrict__ encW, const float* __restrict__ encB,
                     float* __restrict__ ET, int R, int T) {
  int idx = blockIdx.x * 256 + threadIdx.x;
  int total = R * TBK * HH;
  if (idx >= total) return;
  int r = idx / (TBK * HH);
  int rem = idx - r * (TBK * HH);
  int b = rem / HH;
  int h = rem - b * HH;
  float v = 0.0f;
  if (b < T) v = encW[((size_t)r * HH + h) * (size_t)T + b] + encB[r * HH + h];
  ET[idx] = v;
}

__global__ void k_copy(const float4* __restrict__ in, float4* __restrict__ o, long long n4) {
  long long i = (long long)blockIdx.x * blockDim.x + threadIdx.x;
  long long stride = (long long)gridDim.x * blockDim.x;
  for (; i < n4; i += stride) o[i] = in[i];
}

// ---------------- main GRU kernel (MFMA, bf16x2 split precision) ----------------
// One block = MB(=32) winner edges of one relation. 256 threads = 4 waves.
// GEMM: X[32 x 256] (LDS, bf16 hi/lo, XOR-swizzled) x WT[256 x 512] (global bf16 hi/lo)
// Wave w owns channels [w*32, w*32+32): for each 16-channel frag it accumulates the
// matching column-frags of all 4 gates, so the epilogue is pure per-lane math.
__global__ __launch_bounds__(256, 2) void k_gru(
    const float* __restrict__ prev, const float* __restrict__ encW, const float* __restrict__ encB,
    const float* __restrict__ bih, const float* __restrict__ bhh,
    const int* __restrict__ src, const int* __restrict__ dst, const int* __restrict__ te,
    const int* __restrict__ ctp,
    const int* __restrict__ meta, const int* __restrict__ bin,
    const short* __restrict__ WThi, const short* __restrict__ WTlo, const float* __restrict__ ET,
    float* __restrict__ out, int N, int T, int R) {
  // bijective XCD swizzle (m204): contiguous group-chunks per XCD -> per-relation
  // weight slice (~525 KB hi+lo) stays resident in one XCD's L2.
  int nwg = gridDim.x;
  int orig = blockIdx.x;
  int q = nwg >> 3, rm = nwg & 7;
  int xcd = orig & 7, oi = orig >> 3;
  int b = (xcd < rm ? xcd * (q + 1) : rm * (q + 1) + (xcd - rm) * q) + oi;

  int total = meta[50];
  if (b >= total) return;
  int r = 0;
  while (r + 1 < R && b >= meta[33 + r + 1]) r++;
  int g = b - meta[33 + r];
  int i0 = meta[16 + r] + g * MB;
  int mcnt = meta[16 + r + 1] - i0;
  if (mcnt > MB) mcnt = MB;

  __shared__ __align__(16) short Ahi[MB * KK];  // 16 KB
  __shared__ __align__(16) short Alo[MB * KK];  // 16 KB
  __shared__ int sS[MB], sB[MB], sD[MB];

  int t = threadIdx.x;
  if (t < MB) {
    if (t < mcnt) {
      int e = bin[i0 + t];
      sS[t] = src[e];
      sD[t] = dst[e];
      int bk = *ctp - te[e];
      if (bk > T - 1) bk = T - 1;
      sB[t] = bk;
    } else {
      sS[t] = 0; sD[t] = 0; sB[t] = 0;
    }
  }
  __syncthreads();

  // stage x = [encoded + u_j, u_i] as bf16 hi/lo into LDS.
  // Swizzle (shorts): idx = (m*256 + j) ^ ((m&7)<<3)  -> conflict-free ds_read_b128 frags.
  #pragma unroll 4
  for (int m = 0; m < MB; m++) {
    int s = sS[m], d = sD[m], bk = sB[m];
    float v;
    if (t < HH) {
      float enc;
      if (bk < TBK) enc = ET[((size_t)r * TBK + bk) * HH + t];
      else          enc = encW[((size_t)r * HH + t) * (size_t)T + bk] + encB[r * HH + t];
      v = enc + prev[((size_t)r * N + d) * HH + t];
    } else {
      v = prev[((size_t)r * N + s) * HH + (t - HH)];
    }
    short hi = f2bf(v);
    short lo = f2bf(v - bf2f(hi));
    int idx = (m * KK + t) ^ ((m & 7) << 3);
    Ahi[idx] = hi;
    Alo[idx] = lo;
  }
  __syncthreads();

  int lane = t & 63;
  int w = t >> 6;        // wave 0..3
  int lm = lane & 15;    // frag row/col index
  int lg = lane >> 4;    // k-group 0..3

  f32x4 acc[4][2][2];    // [gate][mfrag][cfrag]
  #pragma unroll
  for (int a = 0; a < 4; a++)
    #pragma unroll
    for (int mf = 0; mf < 2; mf++)
      #pragma unroll
      for (int cf = 0; cf < 2; cf++)
        acc[a][mf][cf] = (f32x4){0.f, 0.f, 0.f, 0.f};

  const short* WH = WThi + (size_t)r * NC * KK;
  const short* WL = WTlo + (size_t)r * NC * KK;

  for (int ks = 0; ks < 8; ks++) {      // K = 256 in steps of 32
    bf16x8 ah[2], al[2];
    #pragma unroll
    for (int mf = 0; mf < 2; mf++) {
      int m = mf * 16 + lm;
      int idx = (m * KK + ks * 32 + lg * 8) ^ ((m & 7) << 3);
      ah[mf] = *(const bf16x8*)&Ahi[idx];
      al[mf] = *(const bf16x8*)&Alo[idx];
    }
    #pragma unroll
    for (int cf = 0; cf < 2; cf++) {
      #pragma unroll
      for (int gate = 0; gate < 4; gate++) {
        int c = gate * HH + w * 32 + cf * 16 + lm;            // B col for this lane
        size_t off = (size_t)c * KK + ks * 32 + lg * 8;
        bf16x8 bh = *(const bf16x8*)&WH[off];
        bf16x8 bl = *(const bf16x8*)&WL[off];
        #pragma unroll
        for (int mf = 0; mf < 2; mf++) {
          acc[gate][mf][cf] = __builtin_amdgcn_mfma_f32_16x16x32_bf16(ah[mf], bh, acc[gate][mf][cf], 0, 0, 0);
          acc[gate][mf][cf] = __builtin_amdgcn_mfma_f32_16x16x32_bf16(al[mf], bh, acc[gate][mf][cf], 0, 0, 0);
          acc[gate][mf][cf] = __builtin_amdgcn_mfma_f32_16x16x32_bf16(ah[mf], bl, acc[gate][mf][cf], 0, 0, 0);
        }
      }
    }
  }

  // epilogue: D frag mapping col=lane&15, row=(lane>>4)*4+reg
  #pragma unroll
  for (int cf = 0; cf < 2; cf++) {
    int c = w * 32 + cf * 16 + lm;   // output channel 0..127
    float bR = bih[r * 384 + c]       + bhh[r * 384 + c];
    float bZ = bih[r * 384 + HH + c]  + bhh[r * 384 + HH + c];
    float bN = bih[r * 384 + 2 * HH + c];
    float bH = bhh[r * 384 + 2 * HH + c];
    #pragma unroll
    for (int mf = 0; mf < 2; mf++) {
      #pragma unroll
      for (int reg = 0; reg < 4; reg++) {
        int m = mf * 16 + lg * 4 + reg;
        if (m < mcnt) {
          float sr  = acc[0][mf][cf][reg] + bR;
          float sz  = acc[1][mf][cf][reg] + bZ;
          float in_ = acc[2][mf][cf][reg] + bN;
          float hn  = acc[3][mf][cf][reg] + bH;
          float rg = 1.f / (1.f + __expf(-sr));
          float zg = 1.f / (1.f + __expf(-sz));
          float ng = tanhf(in_ + rg * hn);
          int idxh = (m * KK + HH + c) ^ ((m & 7) << 3);
          float hp = bf2f(Ahi[idxh]) + bf2f(Alo[idxh]);   // h_prev, ~16-bit exact
          out[((size_t)r * N + sS[m]) * HH + c] = (1.f - zg) * ng + zg * hp;
        }
      }
    }
  }
}

// ---------------- launch ----------------

extern "C" void kernel_launch(void* const* d_in, const int* in_sizes, int n_in,
                              void* d_out, int out_size, void* d_ws, size_t ws_size,
                              hipStream_t stream) {
  const float* prev = (const float*)d_in[0];
  const float* encW = (const float*)d_in[1];
  const float* encB = (const float*)d_in[2];
  const float* Wih  = (const float*)d_in[3];
  const float* Whh  = (const float*)d_in[4];
  const float* bih  = (const float*)d_in[5];
  const float* bhh  = (const float*)d_in[6];
  const int* src = (const int*)d_in[7];
  const int* dst = (const int*)d_in[8];
  const int* rel = (const int*)d_in[9];
  const int* te  = (const int*)d_in[10];
  const int* ctp = (const int*)d_in[11];
  float* out = (float*)d_out;

  int E = in_sizes[7];
  int R = in_sizes[5] / 384;            // b_ih is [R,3H]
  int N = in_sizes[0] / (R * HH);
  int T = in_sizes[1] / (2 * R * HH);

  // ws layout (bytes): lastpos[R*N] | meta[128] | bin[E] | WThi | WTlo | ET   (~9.7 MB)
  char* wsb = (char*)d_ws;
  size_t off = 0;
  int* lastpos = (int*)(wsb + off); off += (size_t)R * N * 4;
  int* meta    = (int*)(wsb + off); off += 128 * 4;
  int* bin     = (int*)(wsb + off); off += (size_t)E * 4;
  off = (off + 15) & ~(size_t)15;
  short* WThi = (short*)(wsb + off); off += (size_t)R * NC * KK * 2;
  short* WTlo = (short*)(wsb + off); off += (size_t)R * NC * KK * 2;
  float* ET   = (float*)(wsb + off); off += (size_t)R * TBK * HH * 4;
  (void)ws_size;

  hipMemsetAsync(lastpos, 0xFF, (size_t)R * N * sizeof(int), stream);   // -1
  hipMemsetAsync(meta, 0, 128 * sizeof(int), stream);

  int eb = (E + 255) / 256;
  k_lastpos<<<eb, 256, 0, stream>>>(rel, src, lastpos, N, E);
  k_count<<<eb, 256, 0, stream>>>(rel, src, lastpos, meta, N, E);
  k_scan<<<1, 64, 0, stream>>>(meta, R);
  k_scatter<<<eb, 256, 0, stream>>>(rel, src, lastpos, meta, bin, N, E);

  int tW = R * NC * KK;
  k_wprep<<<(tW + 255) / 256, 256, 0, stream>>>(Wih, Whh, WThi, WTlo, R);
  int tET = R * TBK * HH;
  k_et<<<(tET + 255) / 256, 256, 0, stream>>>(encW, encB, ET, R, T);

  long long n4 = (long long)out_size / 4;
  k_copy<<<8192, 256, 0, stream>>>((const float4*)prev, (float4*)out, n4);

  int gruBlocks = (E + MB - 1) / MB + R;
  k_gru<<<gruBlocks, 256, 0, stream>>>(prev, encW, encB, bih, bhh, src, dst, te, ctp,
                                       meta, bin, WThi, WTlo, ET, out, N, T, R);
}